// Round 17
// baseline (224.174 us; speedup 1.0000x reference)
//
#include <hip/hip_runtime.h>
#include <hip/hip_fp16.h>

// Problem constants (from reference)
constexpr int   kNpixHi = 1024;
constexpr int   kNpixLo = 256;
constexpr int   kNv     = 64;
constexpr float kFov    = 12.7875f;   // 0.5*(1024-1)*0.025
constexpr float kPsHi   = 0.025f;    // hi-res pixel scale
constexpr float kDv     = 10.0f;
constexpr float kVel0   = 0.0f;

// Binning geometry: bin = (iv0 plane-slot 0..63, 128x64 spatial tile 0..7)
// iv0 in [0,62]; slot 63 always empty. Record covers BOTH planes iv0, iv0+1.
constexpr int kTileW        = 128;
constexpr int kTileH        = 64;
constexpr int kTilePix      = kTileW * kTileH;      // 8192
constexpr int kBinsPerPlane = 8;
constexpr int kNumBins      = 64 * kBinsPerPlane;   // 512
constexpr int kBinCapIdeal  = 16384;   // u64 records/bin (expected ~12.4K)
constexpr int kBinCapMin    = 13500;   // below this: fall back
constexpr int kThreadsK1    = 512;     // == kNumBins
constexpr int kWavesK1      = kThreadsK1 / 64;      // 8
constexpr int kSamplesPerBlock = 4096;              // 512 thr x 2 float4
constexpr int kSlice        = 18;      // fixed u64 records/bin in LDS (76 KB)
constexpr int kThreadsK2    = 1024;

typedef unsigned int u32x4 __attribute__((ext_vector_type(4)));
typedef unsigned long long u64;

// Record: u64 = [w1:f16]<<32 | [w0:f16]<<16 | idx(13b)
__device__ __forceinline__ u64 pack_rec(unsigned idx, float w0, float w1) {
  const unsigned pk = (unsigned)__half_as_ushort(__float2half(w0))
                    | ((unsigned)__half_as_ushort(__float2half(w1)) << 16);
  return ((u64)pk << 16) | idx;
}

__device__ __forceinline__ void sys_store64(u64* p, u64 v) {
  __hip_atomic_store(p, v, __ATOMIC_RELAXED, __HIP_MEMORY_SCOPE_SYSTEM);
}

__device__ __forceinline__ __half2 h2_from_u32(unsigned pk) {
  return __builtin_bit_cast(__half2, pk);
}

// register stash for the rare slice-overflow records (static-indexed)
struct Stash {
  unsigned bin0, bin1, bin2, bin3;
  u64 rec0, rec1, rec2, rec3;
  int n;
};

// ---------------------------------------------------------------------------
// emit one pair-record: append to the bin's fixed LDS slice; overflow ->
// register stash (drained after the loop); stash-full -> direct global (rare).
// ---------------------------------------------------------------------------
__device__ __forceinline__ void emit_rec(int bin, unsigned idx, float w0, float w1,
                                         unsigned int* s_cnt, u64* lds_rec,
                                         unsigned int* __restrict__ cursors,
                                         u64* __restrict__ recs,
                                         unsigned int binCap, Stash& st) {
  const u64 rec = pack_rec(idx, w0, w1);
  const unsigned off = atomicAdd(&s_cnt[bin], 1u);
  if (off < (unsigned)kSlice) {
    lds_rec[bin * kSlice + off] = rec;
  } else if (st.n < 4) {
    if      (st.n == 0) { st.bin0 = bin; st.rec0 = rec; }
    else if (st.n == 1) { st.bin1 = bin; st.rec1 = rec; }
    else if (st.n == 2) { st.bin2 = bin; st.rec2 = rec; }
    else                { st.bin3 = bin; st.rec3 = rec; }
    st.n++;
  } else {
    const unsigned slot = atomicAdd(&cursors[bin], 1u);
    if (slot < binCap) sys_store64(&recs[(size_t)bin * binCap + slot], rec);
  }
}

__device__ __forceinline__ void process_sample(float rr, float dd, float vv, float ff,
                                               unsigned int* s_cnt, u64* lds_rec,
                                               unsigned int* __restrict__ cursors,
                                               u64* __restrict__ recs,
                                               unsigned int binCap, Stash& st) {
  const float x = (rr + kFov) / kPsHi;
  const float y = (dd + kFov) / kPsHi;
  const float w = (vv - kVel0) / kDv;

  const float xf = floorf(x), yf = floorf(y), wf = floorf(w);
  const int ix0 = (int)xf, iy0 = (int)yf, iv0 = (int)wf;

  if (ix0 < 0 || ix0 >= kNpixHi - 1 ||
      iy0 < 0 || iy0 >= kNpixHi - 1 ||
      iv0 < 0 || iv0 >= kNv - 1)
    return;

  const float fx = x - xf, fy = y - yf, fv = w - wf;

  // fold the 4x4 box-mean (1/16) into the weight
  const float fw  = ff * 0.0625f;
  const float wv0 = fw * (1.0f - fv);
  const float wv1 = fw * fv;

  // low-res pixels of the two hi-res corners per axis; same pixel -> weights
  // merge exactly ((1-f)+f = 1)
  const int lx0 = ix0 >> 2, lx1 = (ix0 + 1) >> 2;
  const int ly0 = iy0 >> 2, ly1 = (iy0 + 1) >> 2;
  const bool tx = (lx1 != lx0), ty = (ly1 != ly0);
  const float wx0 = tx ? (1.0f - fx) : 1.0f;
  const float wy0 = ty ? (1.0f - fy) : 1.0f;

#define EMIT_PIX(lx, ly, wxy)                                                \
  {                                                                          \
    const int sb  = (((ly) >> 6) << 1) | ((lx) >> 7);                        \
    const int bin = (iv0 << 3) | sb;                                         \
    const unsigned idx = (unsigned)(((ly) & (kTileH - 1)) * kTileW +         \
                                    ((lx) & (kTileW - 1)));                  \
    emit_rec(bin, idx, (wxy) * wv0, (wxy) * wv1,                             \
             s_cnt, lds_rec, cursors, recs, binCap, st);                     \
  }

  EMIT_PIX(lx0, ly0, wx0 * wy0)
  if (tx)       EMIT_PIX(lx1, ly0, fx * wy0)
  if (ty)       EMIT_PIX(lx0, ly1, wx0 * fy)
  if (tx && ty) EMIT_PIX(lx1, ly1, fx * fy)
#undef EMIT_PIX
}

// ---------------------------------------------------------------------------
// K1 (single pass): emit into fixed per-bin LDS slices (register-stash
// overflow) -> per-bin global reserve -> coalesced copy-out.
// ---------------------------------------------------------------------------
__global__ __launch_bounds__(kThreadsK1) void scatter_kernel(
    const float* __restrict__ ra, const float* __restrict__ dec,
    const float* __restrict__ vel, const float* __restrict__ flux,
    u64* __restrict__ recs, unsigned int* __restrict__ cursors,
    int m, unsigned int binCap) {
  __shared__ unsigned int s_cnt[kNumBins];            // 2 KB
  __shared__ unsigned int s_base[kNumBins];           // 2 KB
  __shared__ u64 lds_rec[kNumBins * kSlice];          // 72 KB

  const int tid = threadIdx.x;
  const int blockBase = blockIdx.x * kSamplesPerBlock;
  const int sA = blockBase + tid * 4;                    // chunk 0
  const int sB = blockBase + kThreadsK1 * 4 + tid * 4;   // chunk 1

  float4 rA, dA, vA, fA, rB, dB, vB, fB;

#define LOAD4(s0, r4, d4, v4, f4)                                          \
  if ((s0) + 4 <= m) {                                                     \
    r4 = *reinterpret_cast<const float4*>(ra + (s0));                      \
    d4 = *reinterpret_cast<const float4*>(dec + (s0));                     \
    v4 = *reinterpret_cast<const float4*>(vel + (s0));                     \
    f4 = *reinterpret_cast<const float4*>(flux + (s0));                    \
  } else {                                                                 \
    float* rp = &r4.x; float* dp = &d4.x; float* vp = &v4.x; float* fp = &f4.x; \
    _Pragma("unroll")                                                      \
    for (int k = 0; k < 4; ++k) {                                          \
      const int i = (s0) + k;                                              \
      const bool in = (i < m);                                             \
      rp[k] = in ? ra[i]   : 0.0f;                                         \
      dp[k] = in ? dec[i]  : 0.0f;                                         \
      vp[k] = in ? vel[i]  : -1e9f;                                        \
      fp[k] = in ? flux[i] : 0.0f;                                         \
    }                                                                      \
  }

  LOAD4(sA, rA, dA, vA, fA)
  LOAD4(sB, rB, dB, vB, fB)
#undef LOAD4

  // tid == bin index (kThreadsK1 == kNumBins)
  s_cnt[tid] = 0u;
  __syncthreads();

  Stash st;
  st.n = 0;
  st.bin0 = st.bin1 = st.bin2 = st.bin3 = 0u;
  st.rec0 = st.rec1 = st.rec2 = st.rec3 = 0ull;

  // single emit pass (geometry computed once)
#pragma unroll
  for (int k = 0; k < 4; ++k)
    process_sample((&rA.x)[k], (&dA.x)[k], (&vA.x)[k], (&fA.x)[k],
                   s_cnt, lds_rec, cursors, recs, binCap, st);
#pragma unroll
  for (int k = 0; k < 4; ++k)
    process_sample((&rB.x)[k], (&dB.x)[k], (&vB.x)[k], (&fB.x)[k],
                   s_cnt, lds_rec, cursors, recs, binCap, st);

  // drain stash (rare; ~1.6% of records land here)
  if (st.n > 0) {
    const unsigned slot = atomicAdd(&cursors[st.bin0], 1u);
    if (slot < binCap) sys_store64(&recs[(size_t)st.bin0 * binCap + slot], st.rec0);
  }
  if (st.n > 1) {
    const unsigned slot = atomicAdd(&cursors[st.bin1], 1u);
    if (slot < binCap) sys_store64(&recs[(size_t)st.bin1 * binCap + slot], st.rec1);
  }
  if (st.n > 2) {
    const unsigned slot = atomicAdd(&cursors[st.bin2], 1u);
    if (slot < binCap) sys_store64(&recs[(size_t)st.bin2 * binCap + slot], st.rec2);
  }
  if (st.n > 3) {
    const unsigned slot = atomicAdd(&cursors[st.bin3], 1u);
    if (slot < binCap) sys_store64(&recs[(size_t)st.bin3 * binCap + slot], st.rec3);
  }
  __syncthreads();

  // per-bin global reserve for the LDS-resident slice
  {
    const unsigned c0 = s_cnt[tid];
    const unsigned c  = c0 < (unsigned)kSlice ? c0 : (unsigned)kSlice;
    s_base[tid] = c ? atomicAdd(&cursors[tid], c) : 0u;
    s_cnt[tid]  = c;
  }
  __syncthreads();

  // coalesced copy-out: one bin per wave at a time (cnt <= 18 -> 1 iter)
  const int wave = tid >> 6, lane = tid & 63;
  for (int b = wave; b < kNumBins; b += kWavesK1) {
    const unsigned cnt  = s_cnt[b];
    const unsigned base = s_base[b];
    u64* __restrict__ seg = recs + (size_t)b * binCap;
    for (unsigned j = lane; j < cnt; j += 64) {
      const unsigned slot = base + j;
      if (slot < binCap) sys_store64(&seg[slot], lds_rec[b * kSlice + j]);
    }
  }
}

// ---------------------------------------------------------------------------
// K2 (r16-proven): accumulate bin's records into LDS half2 tile via packed-f16
// atomics, then dump raw tile to staging (plain stores).
// ---------------------------------------------------------------------------
__global__ __launch_bounds__(kThreadsK2) void accum_kernel(
    const u64* __restrict__ recs, const unsigned int* __restrict__ cursors,
    unsigned int* __restrict__ tiles, unsigned int binCap) {
  __shared__ __half2 tile2[kTilePix];   // 32 KB
  const int bin = blockIdx.x;
  const int tid = threadIdx.x;

  for (int i = tid; i < kTilePix; i += kThreadsK2)
    reinterpret_cast<unsigned*>(tile2)[i] = 0u;
  __syncthreads();

  unsigned cnt = cursors[bin];
  if (cnt > binCap) cnt = binCap;
  const u64* __restrict__ rb = recs + (size_t)bin * binCap;
  const u32x4* __restrict__ rb4 = reinterpret_cast<const u32x4*>(rb);

  const unsigned npair = cnt >> 1;   // 2 records per 16B load
  for (unsigned j = (unsigned)tid; j < npair; j += kThreadsK2) {
    const u32x4 q = rb4[j];
    const unsigned idx0 = q.x & 0xFFFFu;
    const unsigned pk0  = (q.x >> 16) | (q.y << 16);
    unsafeAtomicAdd(&tile2[idx0], h2_from_u32(pk0));
    const unsigned idx1 = q.z & 0xFFFFu;
    const unsigned pk1  = (q.z >> 16) | (q.w << 16);
    unsafeAtomicAdd(&tile2[idx1], h2_from_u32(pk1));
  }
  if ((cnt & 1u) && tid == 0) {
    const u64 r = rb[cnt - 1];
    unsafeAtomicAdd(&tile2[(unsigned)r & 0xFFFFu],
                    h2_from_u32((unsigned)(r >> 16)));
  }
  __syncthreads();

  // raw tile dump: 8192 u32 -> staging, fully coalesced
  unsigned int* __restrict__ dst = tiles + (size_t)bin * kTilePix;
  const unsigned* __restrict__ src = reinterpret_cast<const unsigned*>(tile2);
  for (int g = tid; g < kTilePix / 4; g += kThreadsK2) {
    *reinterpret_cast<u32x4*>(dst + g * 4) =
        *reinterpret_cast<const u32x4*>(src + g * 4);
  }
}

// ---------------------------------------------------------------------------
// Convert: out[v][pix] = tiles[v][sb][idx].lo + tiles[v-1][sb][idx].hi (f32)
// ---------------------------------------------------------------------------
__global__ __launch_bounds__(256) void convert_kernel(
    const unsigned int* __restrict__ tiles, float* __restrict__ out) {
  const int t   = blockIdx.x * blockDim.x + threadIdx.x;   // 0 .. 512*2048-1
  const int bin = t >> 11;              // 2048 u32x4-groups per bin
  const int g   = t & 2047;
  const int idx = g * 4;

  const u32x4 cur = *reinterpret_cast<const u32x4*>(
      tiles + (size_t)bin * kTilePix + idx);
  const int v = bin >> 3;
  u32x4 prv = {0u, 0u, 0u, 0u};
  if (v > 0)
    prv = *reinterpret_cast<const u32x4*>(
        tiles + (size_t)(bin - kBinsPerPlane) * kTilePix + idx);

  float4 r;
#pragma unroll
  for (int k = 0; k < 4; ++k) {
    const __half2 c = h2_from_u32(cur[k]);
    const __half2 p = h2_from_u32(prv[k]);
    (&r.x)[k] = __low2float(c) + ((v > 0) ? __high2float(p) : 0.0f);
  }

  const int sb = bin & 7;
  const int ry = idx >> 7, rx = idx & (kTileW - 1);
  const size_t o = (size_t)v * (kNpixLo * kNpixLo)
                 + (size_t)((sb >> 1) * kTileH + ry) * kNpixLo
                 + (size_t)(sb & 1) * kTileW + rx;
  *reinterpret_cast<float4*>(out + o) = r;
}

// ---------------------------------------------------------------------------
// Fallback: direct f32 CAS-atomic kernel if workspace is too small
// ---------------------------------------------------------------------------
__device__ __forceinline__ void splat2(float* __restrict__ out, int planeBase,
                                       int lx, int ly, float wxy,
                                       float wv0, float wv1) {
  const int s = ly * kNpixLo + lx;
  atomicAdd(out + planeBase + s, wxy * wv0);
  atomicAdd(out + planeBase + kNpixLo * kNpixLo + s, wxy * wv1);
}

__global__ __launch_bounds__(256) void cloud_raster_direct(
    const float* __restrict__ ra, const float* __restrict__ dec,
    const float* __restrict__ vel, const float* __restrict__ flux,
    float* __restrict__ out, int m) {
  const int t    = blockIdx.x * blockDim.x + threadIdx.x;
  const int base = t * 4;
  if (base >= m) return;
  float4 r4, d4, v4, f4;
  if (base + 4 <= m) {
    r4 = *reinterpret_cast<const float4*>(ra + base);
    d4 = *reinterpret_cast<const float4*>(dec + base);
    v4 = *reinterpret_cast<const float4*>(vel + base);
    f4 = *reinterpret_cast<const float4*>(flux + base);
  } else {
    float* rp = &r4.x; float* dp = &d4.x; float* vp = &v4.x; float* fp = &f4.x;
#pragma unroll
    for (int k = 0; k < 4; ++k) {
      const int i = base + k;
      rp[k] = (i < m) ? ra[i]   : 0.0f;
      dp[k] = (i < m) ? dec[i]  : 0.0f;
      vp[k] = (i < m) ? vel[i]  : -1e9f;
      fp[k] = (i < m) ? flux[i] : 0.0f;
    }
  }
#pragma unroll
  for (int k = 0; k < 4; ++k) {
    const float rr = (&r4.x)[k], dd = (&d4.x)[k], vv = (&v4.x)[k], ff = (&f4.x)[k];
    const float x = (rr + kFov) / kPsHi;
    const float y = (dd + kFov) / kPsHi;
    const float w = (vv - kVel0) / kDv;
    const float xf = floorf(x), yf = floorf(y), wf = floorf(w);
    const int ix0 = (int)xf, iy0 = (int)yf, iv0 = (int)wf;
    if (ix0 < 0 || ix0 >= kNpixHi - 1 || iy0 < 0 || iy0 >= kNpixHi - 1 ||
        iv0 < 0 || iv0 >= kNv - 1)
      continue;
    const float fx = x - xf, fy = y - yf, fv = w - wf;
    const float fw  = ff * 0.0625f;
    const float wv0 = fw * (1.0f - fv);
    const float wv1 = fw * fv;
    const int lx0 = ix0 >> 2, lx1 = (ix0 + 1) >> 2;
    const int ly0 = iy0 >> 2, ly1 = (iy0 + 1) >> 2;
    const bool tx = (lx1 != lx0), ty = (ly1 != ly0);
    const float wx0 = tx ? (1.0f - fx) : 1.0f;
    const float wy0 = ty ? (1.0f - fy) : 1.0f;
    const int pb = iv0 * (kNpixLo * kNpixLo);
    splat2(out, pb, lx0, ly0, wx0 * wy0, wv0, wv1);
    if (tx)       splat2(out, pb, lx1, ly0, fx  * wy0, wv0, wv1);
    if (ty)       splat2(out, pb, lx0, ly1, wx0 * fy,  wv0, wv1);
    if (tx && ty) splat2(out, pb, lx1, ly1, fx  * fy,  wv0, wv1);
  }
}

// ---------------------------------------------------------------------------

extern "C" void kernel_launch(void* const* d_in, const int* in_sizes, int n_in,
                              void* d_out, int out_size, void* d_ws, size_t ws_size,
                              hipStream_t stream) {
  (void)n_in;
  const float* ra   = (const float*)d_in[0];
  const float* dec  = (const float*)d_in[1];
  const float* vel  = (const float*)d_in[2];
  const float* flux = (const float*)d_in[3];
  float* out = (float*)d_out;
  const int m = in_sizes[0];

  // ws layout: [cursors 4KB][tiles 16MB][recs binCap*512*8B]
  constexpr size_t kCursorBytes = 4096;
  constexpr size_t kTileBytes   = (size_t)kNumBins * kTilePix * 4;   // 16 MB
  unsigned int binCap = 0;
  if (ws_size > kCursorBytes + kTileBytes) {
    const size_t avail = (ws_size - kCursorBytes - kTileBytes) / ((size_t)kNumBins * 8);
    binCap = (unsigned int)(avail < (size_t)kBinCapIdeal ? avail : (size_t)kBinCapIdeal);
    binCap &= ~1u;   // keep 16B alignment for u32x4 reads in K2
  }

  if (binCap >= kBinCapMin) {
    unsigned int* cursors = (unsigned int*)d_ws;
    unsigned int* tiles   = (unsigned int*)((char*)d_ws + kCursorBytes);
    u64* recs = (u64*)((char*)d_ws + kCursorBytes + kTileBytes);
    hipError_t e = hipMemsetAsync(d_ws, 0, kCursorBytes, stream); (void)e;
    const int blocks = (m + kSamplesPerBlock - 1) / kSamplesPerBlock;
    scatter_kernel<<<blocks, kThreadsK1, 0, stream>>>(ra, dec, vel, flux, recs, cursors, m, binCap);
    accum_kernel<<<kNumBins, kThreadsK2, 0, stream>>>(recs, cursors, tiles, binCap);
    convert_kernel<<<(kNumBins * (kTilePix / 4)) / 256, 256, 0, stream>>>(tiles, out);
  } else {
    // workspace too small: CAS f32-atomic fallback
    hipError_t e = hipMemsetAsync(d_out, 0, (size_t)out_size * sizeof(float), stream); (void)e;
    const int threads = 256;
    const int nThreads = (m + 3) / 4;
    const int blocks = (nThreads + threads - 1) / threads;
    cloud_raster_direct<<<blocks, threads, 0, stream>>>(ra, dec, vel, flux, out, m);
  }
}

// Round 18
// 106.672 us; speedup vs baseline: 2.1015x; 2.1015x over previous
//
#include <hip/hip_runtime.h>
#include <hip/hip_fp16.h>

// Problem constants (from reference)
constexpr int   kNpixHi = 1024;
constexpr int   kNpixLo = 256;
constexpr int   kNv     = 64;
constexpr float kFov    = 12.7875f;   // 0.5*(1024-1)*0.025
constexpr float kInvPsHi = 40.0f;     // 1 / 0.025 (recip-mul: trilinear is
constexpr float kInvDv   = 0.1f;      // continuous across cell boundaries,
constexpr float kVel0    = 0.0f;      // so floor-flip error is ~ulp-scale)

// Binning geometry: bin = (iv0 plane-slot 0..63, 128x64 spatial tile 0..7)
// iv0 in [0,62]; slot 63 always empty. Record covers BOTH planes iv0, iv0+1.
constexpr int kTileW        = 128;
constexpr int kTileH        = 64;
constexpr int kTilePix      = kTileW * kTileH;      // 8192
constexpr int kBinsPerPlane = 8;
constexpr int kNumBins      = 64 * kBinsPerPlane;   // 512
constexpr int kBinCapIdeal  = 16384;   // u64 records/bin (expected ~12.4K)
constexpr int kBinCapMin    = 13500;   // below this: fall back
constexpr int kThreadsK1    = 512;     // == kNumBins (scan uses this)
constexpr int kWavesK1      = kThreadsK1 / 64;      // 8
constexpr int kSamplesPerBlock = 4096;              // 512 thr x 2 float4
constexpr int kLdsRecCap    = 8192;    // u64 LDS staging (64 KB); mean ~6.4K
constexpr int kThreadsK2    = 1024;

typedef unsigned int u32x4 __attribute__((ext_vector_type(4)));
typedef unsigned long long u64;

// Record: u64 = [w1:f16]<<32 | [w0:f16]<<16 | idx(13b)
__device__ __forceinline__ u64 pack_rec(unsigned idx, float w0, float w1) {
  const unsigned pk = (unsigned)__half_as_ushort(__float2half(w0))
                    | ((unsigned)__half_as_ushort(__float2half(w1)) << 16);
  return ((u64)pk << 16) | idx;
}

__device__ __forceinline__ void sys_store64(u64* p, u64 v) {
  __hip_atomic_store(p, v, __ATOMIC_RELAXED, __HIP_MEMORY_SCOPE_SYSTEM);
}

__device__ __forceinline__ __half2 h2_from_u32(unsigned pk) {
  return __builtin_bit_cast(__half2, pk);
}

enum EmitMode { kCount, kLds, kDirect };

// ---------------------------------------------------------------------------
// emit one pair-record (count / LDS-compact / direct-global)
// ---------------------------------------------------------------------------
template <EmitMode MODE>
__device__ __forceinline__ void emit(int bin, unsigned idx, float w0, float w1,
                                     unsigned int* s_cnt,
                                     const unsigned int* s_base,
                                     const unsigned int* s_ofs,
                                     u64* lds_rec,
                                     u64* __restrict__ recs,
                                     unsigned int binCap) {
  if (MODE == kCount) {
    atomicAdd(&s_cnt[bin], 1u);
    return;
  }
  const unsigned off = atomicAdd(&s_cnt[bin], 1u);
  if (MODE == kLds) {
    lds_rec[s_ofs[bin] + off] = pack_rec(idx, w0, w1);
  } else {
    const unsigned slot = s_base[bin] + off;
    if (slot < binCap)
      sys_store64(&recs[(size_t)bin * binCap + slot], pack_rec(idx, w0, w1));
  }
}

template <EmitMode MODE>
__device__ __forceinline__ void process_sample(float rr, float dd, float vv, float ff,
                                               unsigned int* s_cnt,
                                               const unsigned int* s_base,
                                               const unsigned int* s_ofs,
                                               u64* lds_rec,
                                               u64* __restrict__ recs,
                                               unsigned int binCap) {
  const float x = (rr + kFov) * kInvPsHi;
  const float y = (dd + kFov) * kInvPsHi;
  const float w = (vv - kVel0) * kInvDv;

  const float xf = floorf(x), yf = floorf(y), wf = floorf(w);
  const int ix0 = (int)xf, iy0 = (int)yf, iv0 = (int)wf;

  if (ix0 < 0 || ix0 >= kNpixHi - 1 ||
      iy0 < 0 || iy0 >= kNpixHi - 1 ||
      iv0 < 0 || iv0 >= kNv - 1)
    return;

  const float fx = x - xf, fy = y - yf, fv = w - wf;

  // fold the 4x4 box-mean (1/16) into the weight
  const float fw  = ff * 0.0625f;
  const float wv0 = fw * (1.0f - fv);
  const float wv1 = fw * fv;

  // low-res pixels of the two hi-res corners per axis; same pixel -> weights
  // merge exactly ((1-f)+f = 1)
  const int lx0 = ix0 >> 2, lx1 = (ix0 + 1) >> 2;
  const int ly0 = iy0 >> 2, ly1 = (iy0 + 1) >> 2;
  const bool tx = (lx1 != lx0), ty = (ly1 != ly0);
  const float wx0 = tx ? (1.0f - fx) : 1.0f;
  const float wy0 = ty ? (1.0f - fy) : 1.0f;

#define EMIT_PIX(lx, ly, wxy)                                                \
  {                                                                          \
    const int sb  = (((ly) >> 6) << 1) | ((lx) >> 7);                        \
    const int bin = (iv0 << 3) | sb;                                         \
    const unsigned idx = (unsigned)(((ly) & (kTileH - 1)) * kTileW +         \
                                    ((lx) & (kTileW - 1)));                  \
    emit<MODE>(bin, idx, (wxy) * wv0, (wxy) * wv1,                           \
               s_cnt, s_base, s_ofs, lds_rec, recs, binCap);                 \
  }

  EMIT_PIX(lx0, ly0, wx0 * wy0)
  if (tx)       EMIT_PIX(lx1, ly0, fx * wy0)
  if (ty)       EMIT_PIX(lx0, ly1, wx0 * fy)
  if (tx && ty) EMIT_PIX(lx1, ly1, fx * fy)
#undef EMIT_PIX
}

// ---------------------------------------------------------------------------
// K1 (r16-proven): count -> block prefix-scan + global reserve -> LDS-compact
// records -> coalesced per-bin copy-out. Inputs read ONCE into registers.
// ---------------------------------------------------------------------------
__global__ __launch_bounds__(kThreadsK1) void scatter_kernel(
    const float* __restrict__ ra, const float* __restrict__ dec,
    const float* __restrict__ vel, const float* __restrict__ flux,
    u64* __restrict__ recs, unsigned int* __restrict__ cursors,
    int m, unsigned int binCap) {
  __shared__ unsigned int s_cnt[kNumBins];
  __shared__ unsigned int s_base[kNumBins];
  __shared__ unsigned int s_ofs[kNumBins];
  __shared__ unsigned int s_wbase[kWavesK1];
  __shared__ unsigned int s_wsum[kWavesK1];
  __shared__ unsigned int s_total;
  __shared__ u64 lds_rec[kLdsRecCap];   // 64 KB staging

  const int tid = threadIdx.x;
  const int blockBase = blockIdx.x * kSamplesPerBlock;
  const int sA = blockBase + tid * 4;                    // chunk 0
  const int sB = blockBase + kThreadsK1 * 4 + tid * 4;   // chunk 1

  float4 rA, dA, vA, fA, rB, dB, vB, fB;

#define LOAD4(s0, r4, d4, v4, f4)                                          \
  if ((s0) + 4 <= m) {                                                     \
    r4 = *reinterpret_cast<const float4*>(ra + (s0));                      \
    d4 = *reinterpret_cast<const float4*>(dec + (s0));                     \
    v4 = *reinterpret_cast<const float4*>(vel + (s0));                     \
    f4 = *reinterpret_cast<const float4*>(flux + (s0));                    \
  } else {                                                                 \
    float* rp = &r4.x; float* dp = &d4.x; float* vp = &v4.x; float* fp = &f4.x; \
    _Pragma("unroll")                                                      \
    for (int k = 0; k < 4; ++k) {                                          \
      const int i = (s0) + k;                                              \
      const bool in = (i < m);                                             \
      rp[k] = in ? ra[i]   : 0.0f;                                         \
      dp[k] = in ? dec[i]  : 0.0f;                                         \
      vp[k] = in ? vel[i]  : -1e9f;                                        \
      fp[k] = in ? flux[i] : 0.0f;                                         \
    }                                                                      \
  }

  LOAD4(sA, rA, dA, vA, fA)
  LOAD4(sB, rB, dB, vB, fB)
#undef LOAD4

  // tid == bin index (kThreadsK1 == kNumBins)
  s_cnt[tid] = 0u;
  __syncthreads();

  // phase 1: count records per bin
#pragma unroll
  for (int k = 0; k < 4; ++k)
    process_sample<kCount>((&rA.x)[k], (&dA.x)[k], (&vA.x)[k], (&fA.x)[k],
                           s_cnt, s_base, s_ofs, lds_rec, recs, binCap);
#pragma unroll
  for (int k = 0; k < 4; ++k)
    process_sample<kCount>((&rB.x)[k], (&dB.x)[k], (&vB.x)[k], (&fB.x)[k],
                           s_cnt, s_base, s_ofs, lds_rec, recs, binCap);
  __syncthreads();

  // block-wide exclusive scan of s_cnt (512 entries, one per thread)
  const unsigned c = s_cnt[tid];
  unsigned v = c;
#pragma unroll
  for (int d = 1; d < 64; d <<= 1) {
    const unsigned n = __shfl_up(v, d, 64);
    if ((tid & 63) >= d) v += n;
  }
  if ((tid & 63) == 63) s_wsum[tid >> 6] = v;
  __syncthreads();
  if (tid == 0) {
    unsigned acc = 0;
#pragma unroll
    for (int i = 0; i < kWavesK1; ++i) { s_wbase[i] = acc; acc += s_wsum[i]; }
    s_total = acc;
  }
  __syncthreads();
  s_ofs[tid]  = s_wbase[tid >> 6] + v - c;                 // exclusive prefix
  s_base[tid] = c ? atomicAdd(&cursors[tid], c) : 0u;      // global reserve
  s_cnt[tid]  = 0u;                                        // reset cursors
  __syncthreads();

  const bool ldsPath = (s_total <= (unsigned)kLdsRecCap);

  if (ldsPath) {
    // phase 2a: compact records into LDS
#pragma unroll
    for (int k = 0; k < 4; ++k)
      process_sample<kLds>((&rA.x)[k], (&dA.x)[k], (&vA.x)[k], (&fA.x)[k],
                           s_cnt, s_base, s_ofs, lds_rec, recs, binCap);
#pragma unroll
    for (int k = 0; k < 4; ++k)
      process_sample<kLds>((&rB.x)[k], (&dB.x)[k], (&vB.x)[k], (&fB.x)[k],
                           s_cnt, s_base, s_ofs, lds_rec, recs, binCap);
    __syncthreads();

    // phase 2b: coalesced copy-out, one bin per wave at a time
    const int wave = tid >> 6, lane = tid & 63;
    for (int b = wave; b < kNumBins; b += kWavesK1) {
      const unsigned cnt  = s_cnt[b];
      const unsigned ofs  = s_ofs[b];
      const unsigned base = s_base[b];
      u64* __restrict__ seg = recs + (size_t)b * binCap;
      for (unsigned j = lane; j < cnt; j += 64) {
        const unsigned slot = base + j;
        if (slot < binCap) sys_store64(&seg[slot], lds_rec[ofs + j]);
      }
    }
  } else {
    // overflow fallback (deterministic per-block): direct scattered stores
#pragma unroll
    for (int k = 0; k < 4; ++k)
      process_sample<kDirect>((&rA.x)[k], (&dA.x)[k], (&vA.x)[k], (&fA.x)[k],
                              s_cnt, s_base, s_ofs, lds_rec, recs, binCap);
#pragma unroll
    for (int k = 0; k < 4; ++k)
      process_sample<kDirect>((&rB.x)[k], (&dB.x)[k], (&vB.x)[k], (&fB.x)[k],
                              s_cnt, s_base, s_ofs, lds_rec, recs, binCap);
  }
}

// ---------------------------------------------------------------------------
// K2 (r16-proven): accumulate bin's records into LDS half2 tile via packed-f16
// atomics, then dump raw tile to staging (plain stores).
// ---------------------------------------------------------------------------
__global__ __launch_bounds__(kThreadsK2) void accum_kernel(
    const u64* __restrict__ recs, const unsigned int* __restrict__ cursors,
    unsigned int* __restrict__ tiles, unsigned int binCap) {
  __shared__ __half2 tile2[kTilePix];   // 32 KB
  const int bin = blockIdx.x;
  const int tid = threadIdx.x;

  for (int i = tid; i < kTilePix; i += kThreadsK2)
    reinterpret_cast<unsigned*>(tile2)[i] = 0u;
  __syncthreads();

  unsigned cnt = cursors[bin];
  if (cnt > binCap) cnt = binCap;
  const u64* __restrict__ rb = recs + (size_t)bin * binCap;
  const u32x4* __restrict__ rb4 = reinterpret_cast<const u32x4*>(rb);

  const unsigned npair = cnt >> 1;   // 2 records per 16B load
  for (unsigned j = (unsigned)tid; j < npair; j += kThreadsK2) {
    const u32x4 q = rb4[j];
    const unsigned idx0 = q.x & 0xFFFFu;
    const unsigned pk0  = (q.x >> 16) | (q.y << 16);
    unsafeAtomicAdd(&tile2[idx0], h2_from_u32(pk0));
    const unsigned idx1 = q.z & 0xFFFFu;
    const unsigned pk1  = (q.z >> 16) | (q.w << 16);
    unsafeAtomicAdd(&tile2[idx1], h2_from_u32(pk1));
  }
  if ((cnt & 1u) && tid == 0) {
    const u64 r = rb[cnt - 1];
    unsafeAtomicAdd(&tile2[(unsigned)r & 0xFFFFu],
                    h2_from_u32((unsigned)(r >> 16)));
  }
  __syncthreads();

  // raw tile dump: 8192 u32 -> staging, fully coalesced
  unsigned int* __restrict__ dst = tiles + (size_t)bin * kTilePix;
  const unsigned* __restrict__ src = reinterpret_cast<const unsigned*>(tile2);
  for (int g = tid; g < kTilePix / 4; g += kThreadsK2) {
    *reinterpret_cast<u32x4*>(dst + g * 4) =
        *reinterpret_cast<const u32x4*>(src + g * 4);
  }
}

// ---------------------------------------------------------------------------
// Convert: out[v][pix] = tiles[v][sb][idx].lo + tiles[v-1][sb][idx].hi (f32)
// ---------------------------------------------------------------------------
__global__ __launch_bounds__(256) void convert_kernel(
    const unsigned int* __restrict__ tiles, float* __restrict__ out) {
  const int t   = blockIdx.x * blockDim.x + threadIdx.x;   // 0 .. 512*2048-1
  const int bin = t >> 11;              // 2048 u32x4-groups per bin
  const int g   = t & 2047;
  const int idx = g * 4;

  const u32x4 cur = *reinterpret_cast<const u32x4*>(
      tiles + (size_t)bin * kTilePix + idx);
  const int v = bin >> 3;
  u32x4 prv = {0u, 0u, 0u, 0u};
  if (v > 0)
    prv = *reinterpret_cast<const u32x4*>(
        tiles + (size_t)(bin - kBinsPerPlane) * kTilePix + idx);

  float4 r;
#pragma unroll
  for (int k = 0; k < 4; ++k) {
    const __half2 c = h2_from_u32(cur[k]);
    const __half2 p = h2_from_u32(prv[k]);
    (&r.x)[k] = __low2float(c) + ((v > 0) ? __high2float(p) : 0.0f);
  }

  const int sb = bin & 7;
  const int ry = idx >> 7, rx = idx & (kTileW - 1);
  const size_t o = (size_t)v * (kNpixLo * kNpixLo)
                 + (size_t)((sb >> 1) * kTileH + ry) * kNpixLo
                 + (size_t)(sb & 1) * kTileW + rx;
  *reinterpret_cast<float4*>(out + o) = r;
}

// ---------------------------------------------------------------------------
// Fallback: direct f32 CAS-atomic kernel if workspace is too small
// ---------------------------------------------------------------------------
__device__ __forceinline__ void splat2(float* __restrict__ out, int planeBase,
                                       int lx, int ly, float wxy,
                                       float wv0, float wv1) {
  const int s = ly * kNpixLo + lx;
  atomicAdd(out + planeBase + s, wxy * wv0);
  atomicAdd(out + planeBase + kNpixLo * kNpixLo + s, wxy * wv1);
}

__global__ __launch_bounds__(256) void cloud_raster_direct(
    const float* __restrict__ ra, const float* __restrict__ dec,
    const float* __restrict__ vel, const float* __restrict__ flux,
    float* __restrict__ out, int m) {
  const int t    = blockIdx.x * blockDim.x + threadIdx.x;
  const int base = t * 4;
  if (base >= m) return;
  float4 r4, d4, v4, f4;
  if (base + 4 <= m) {
    r4 = *reinterpret_cast<const float4*>(ra + base);
    d4 = *reinterpret_cast<const float4*>(dec + base);
    v4 = *reinterpret_cast<const float4*>(vel + base);
    f4 = *reinterpret_cast<const float4*>(flux + base);
  } else {
    float* rp = &r4.x; float* dp = &d4.x; float* vp = &v4.x; float* fp = &f4.x;
#pragma unroll
    for (int k = 0; k < 4; ++k) {
      const int i = base + k;
      rp[k] = (i < m) ? ra[i]   : 0.0f;
      dp[k] = (i < m) ? dec[i]  : 0.0f;
      vp[k] = (i < m) ? vel[i]  : -1e9f;
      fp[k] = (i < m) ? flux[i] : 0.0f;
    }
  }
#pragma unroll
  for (int k = 0; k < 4; ++k) {
    const float rr = (&r4.x)[k], dd = (&d4.x)[k], vv = (&v4.x)[k], ff = (&f4.x)[k];
    const float x = (rr + kFov) * kInvPsHi;
    const float y = (dd + kFov) * kInvPsHi;
    const float w = (vv - kVel0) * kInvDv;
    const float xf = floorf(x), yf = floorf(y), wf = floorf(w);
    const int ix0 = (int)xf, iy0 = (int)yf, iv0 = (int)wf;
    if (ix0 < 0 || ix0 >= kNpixHi - 1 || iy0 < 0 || iy0 >= kNpixHi - 1 ||
        iv0 < 0 || iv0 >= kNv - 1)
      continue;
    const float fx = x - xf, fy = y - yf, fv = w - wf;
    const float fw  = ff * 0.0625f;
    const float wv0 = fw * (1.0f - fv);
    const float wv1 = fw * fv;
    const int lx0 = ix0 >> 2, lx1 = (ix0 + 1) >> 2;
    const int ly0 = iy0 >> 2, ly1 = (iy0 + 1) >> 2;
    const bool tx = (lx1 != lx0), ty = (ly1 != ly0);
    const float wx0 = tx ? (1.0f - fx) : 1.0f;
    const float wy0 = ty ? (1.0f - fy) : 1.0f;
    const int pb = iv0 * (kNpixLo * kNpixLo);
    splat2(out, pb, lx0, ly0, wx0 * wy0, wv0, wv1);
    if (tx)       splat2(out, pb, lx1, ly0, fx  * wy0, wv0, wv1);
    if (ty)       splat2(out, pb, lx0, ly1, wx0 * fy,  wv0, wv1);
    if (tx && ty) splat2(out, pb, lx1, ly1, fx  * fy,  wv0, wv1);
  }
}

// ---------------------------------------------------------------------------

extern "C" void kernel_launch(void* const* d_in, const int* in_sizes, int n_in,
                              void* d_out, int out_size, void* d_ws, size_t ws_size,
                              hipStream_t stream) {
  (void)n_in;
  const float* ra   = (const float*)d_in[0];
  const float* dec  = (const float*)d_in[1];
  const float* vel  = (const float*)d_in[2];
  const float* flux = (const float*)d_in[3];
  float* out = (float*)d_out;
  const int m = in_sizes[0];

  // ws layout: [cursors 4KB][tiles 16MB][recs binCap*512*8B]
  constexpr size_t kCursorBytes = 4096;
  constexpr size_t kTileBytes   = (size_t)kNumBins * kTilePix * 4;   // 16 MB
  unsigned int binCap = 0;
  if (ws_size > kCursorBytes + kTileBytes) {
    const size_t avail = (ws_size - kCursorBytes - kTileBytes) / ((size_t)kNumBins * 8);
    binCap = (unsigned int)(avail < (size_t)kBinCapIdeal ? avail : (size_t)kBinCapIdeal);
    binCap &= ~1u;   // keep 16B alignment for u32x4 reads in K2
  }

  if (binCap >= kBinCapMin) {
    unsigned int* cursors = (unsigned int*)d_ws;
    unsigned int* tiles   = (unsigned int*)((char*)d_ws + kCursorBytes);
    u64* recs = (u64*)((char*)d_ws + kCursorBytes + kTileBytes);
    hipError_t e = hipMemsetAsync(d_ws, 0, kCursorBytes, stream); (void)e;
    const int blocks = (m + kSamplesPerBlock - 1) / kSamplesPerBlock;
    scatter_kernel<<<blocks, kThreadsK1, 0, stream>>>(ra, dec, vel, flux, recs, cursors, m, binCap);
    accum_kernel<<<kNumBins, kThreadsK2, 0, stream>>>(recs, cursors, tiles, binCap);
    convert_kernel<<<(kNumBins * (kTilePix / 4)) / 256, 256, 0, stream>>>(tiles, out);
  } else {
    // workspace too small: CAS f32-atomic fallback
    hipError_t e = hipMemsetAsync(d_out, 0, (size_t)out_size * sizeof(float), stream); (void)e;
    const int threads = 256;
    const int nThreads = (m + 3) / 4;
    const int blocks = (nThreads + threads - 1) / threads;
    cloud_raster_direct<<<blocks, threads, 0, stream>>>(ra, dec, vel, flux, out, m);
  }
}